// Round 1
// baseline (182.234 us; speedup 1.0000x reference)
//
#include <hip/hip_runtime.h>
#include <hip/hip_bf16.h>
#include <stdint.h>

#define BATCH 4096
#define N_TOT 8192
#define D_DIM 256
#define SHIFT 150.0f
#define SQRT2 1.41421356237309515f

typedef __bf16 bf16_t;
typedef bf16_t bf16x8 __attribute__((ext_vector_type(8)));
typedef bf16_t bf16x4 __attribute__((ext_vector_type(4)));
typedef float f32x4 __attribute__((ext_vector_type(4)));

// global -> LDS direct copy, 16B per lane. LDS dest is wave-uniform base;
// HW scatters lane*16B. AS3 offset = low 32 bits of the generic pointer.
__device__ __forceinline__ void gl_lds16(const void* g, void* l) {
  __builtin_amdgcn_global_load_lds(
      (const __attribute__((address_space(1))) void*)(uintptr_t)g,
      (__attribute__((address_space(3))) void*)(uint32_t)(uintptr_t)l,
      16, 0, 0);
}

// hb[n][k] = bf16(h[n][k] * sqrt(2))  -- folds the 1/temp=2 into the GEMM
__global__ void k_convert(const float* __restrict__ hi, const float* __restrict__ hj,
                          bf16_t* __restrict__ hb) {
  int t = blockIdx.x * 256 + threadIdx.x;
  int idx = t * 4;
  const float* src = (idx < BATCH * D_DIM) ? (hi + idx) : (hj + (idx - BATCH * D_DIM));
  float4 v = *(const float4*)src;
  bf16x4 o;
  o[0] = (bf16_t)(v.x * SQRT2);
  o[1] = (bf16_t)(v.y * SQRT2);
  o[2] = (bf16_t)(v.z * SQRT2);
  o[3] = (bf16_t)(v.w * SQRT2);
  *(bf16x4*)(hb + idx) = o;
}

// accs[1] += sum_b 2*dot(h_i[b], h_j[b])   (fp32, exact path for positives)
__global__ void k_pos(const float* __restrict__ hi, const float* __restrict__ hj,
                      float* __restrict__ accs) {
  int gw = (blockIdx.x * 256 + threadIdx.x) >> 6;  // wave id = row b, 0..4095
  int lane = threadIdx.x & 63;
  size_t off = (size_t)gw * D_DIM + lane * 4;
  float4 a = *(const float4*)(hi + off);
  float4 b = *(const float4*)(hj + off);
  float d = a.x * b.x + a.y * b.y + a.z * b.z + a.w * b.w;
#pragma unroll
  for (int o = 32; o >= 1; o >>= 1) d += __shfl_xor(d, o);
  __shared__ float ps[4];
  if (lane == 0) ps[threadIdx.x >> 6] = d;
  __syncthreads();
  if (threadIdx.x == 0) atomicAdd(&accs[1], 2.0f * (ps[0] + ps[1] + ps[2] + ps[3]));
}

// 128x128 tile GEMM (hb . hb^T), fused exp(sim-150) row-accumulate into Zrow.
__global__ __launch_bounds__(256, 2) void k_gemm(const bf16_t* __restrict__ hb,
                                                 float* __restrict__ Zrow) {
  __shared__ __align__(16) bf16_t As[128][64];
  __shared__ __align__(16) bf16_t Bs[128][64];
  const int tid = threadIdx.x;
  const int lane = tid & 63;
  const int wave = tid >> 6;
  const int rBase = blockIdx.y * 128;
  const int cBase = blockIdx.x * 128;

  // staging: waves 0,1 -> As halves; waves 2,3 -> Bs halves. 8 issues x 1KB each.
  const int half = wave & 1;
  const size_t stageRow = (size_t)((wave < 2 ? rBase : cBase) + half * 64);
  const bf16_t* gsrc = hb + stageRow * D_DIM + (size_t)(lane >> 3) * D_DIM + (lane & 7) * 8;
  bf16_t* lbase = (wave < 2) ? &As[half * 64][0] : &Bs[half * 64][0];

  const int wm = wave >> 1, wn = wave & 1;
  const int quad = lane >> 4, l16 = lane & 15;

  f32x4 acc[4][4];
#pragma unroll
  for (int i = 0; i < 4; ++i)
#pragma unroll
    for (int j = 0; j < 4; ++j) acc[i][j] = (f32x4){0.f, 0.f, 0.f, 0.f};

#pragma unroll
  for (int kc = 0; kc < 4; ++kc) {
    __syncthreads();  // prior compute done before overwriting LDS
#pragma unroll
    for (int i = 0; i < 8; ++i)
      gl_lds16(gsrc + (size_t)i * 8 * D_DIM + kc * 64, lbase + i * 8 * 64);
    __syncthreads();  // compiler drains vmcnt before s_barrier
#pragma unroll
    for (int ks = 0; ks < 2; ++ks) {
      bf16x8 af[4], bfr[4];
#pragma unroll
      for (int mt = 0; mt < 4; ++mt)
        af[mt] = *(const bf16x8*)&As[wm * 64 + mt * 16 + l16][ks * 32 + quad * 8];
#pragma unroll
      for (int nt = 0; nt < 4; ++nt)
        bfr[nt] = *(const bf16x8*)&Bs[wn * 64 + nt * 16 + l16][ks * 32 + quad * 8];
#pragma unroll
      for (int mt = 0; mt < 4; ++mt)
#pragma unroll
        for (int nt = 0; nt < 4; ++nt)
          acc[mt][nt] = __builtin_amdgcn_mfma_f32_16x16x32_bf16(af[mt], bfr[nt],
                                                                acc[mt][nt], 0, 0, 0);
    }
  }

  // epilogue: e = exp(sim - 150), mask diagonal, reduce 16 lanes -> row partial
  const int rW = rBase + wm * 64 + quad * 4;
  const int cW = cBase + wn * 64 + l16;
#pragma unroll
  for (int mt = 0; mt < 4; ++mt) {
#pragma unroll
    for (int rg = 0; rg < 4; ++rg) {
      const int rr = rW + mt * 16 + rg;
      float s = 0.f;
#pragma unroll
      for (int nt = 0; nt < 4; ++nt) {
        const int cc = cW + nt * 16;
        float e = __expf(acc[mt][nt][rg] - SHIFT);
        s += (rr == cc) ? 0.f : e;   // diagonal: exp is +inf but never selected
      }
      s += __shfl_xor(s, 1);
      s += __shfl_xor(s, 2);
      s += __shfl_xor(s, 4);
      s += __shfl_xor(s, 8);
      if (l16 == 0) atomicAdd(&Zrow[rr], s);  // 4 lanes (one per quad), distinct rows
    }
  }
}

// accs[0] += sum_r log(Z_r) + 150
__global__ void k_lse(const float* __restrict__ Zrow, float* __restrict__ accs) {
  int t = blockIdx.x * 256 + threadIdx.x;  // 0..8191
  float v = __logf(Zrow[t]) + SHIFT;
#pragma unroll
  for (int o = 32; o >= 1; o >>= 1) v += __shfl_xor(v, o);
  __shared__ float ps[4];
  int lane = threadIdx.x & 63;
  if (lane == 0) ps[threadIdx.x >> 6] = v;
  __syncthreads();
  if (threadIdx.x == 0) atomicAdd(&accs[0], ps[0] + ps[1] + ps[2] + ps[3]);
}

__global__ void k_final(const float* __restrict__ accs, float* __restrict__ out) {
  out[0] = accs[0] / (float)N_TOT - accs[1] / (float)BATCH;
}

extern "C" void kernel_launch(void* const* d_in, const int* in_sizes, int n_in,
                              void* d_out, int out_size, void* d_ws, size_t ws_size,
                              hipStream_t stream) {
  const float* hi = (const float*)d_in[0];
  const float* hj = (const float*)d_in[1];
  float* out = (float*)d_out;

  bf16_t* hb = (bf16_t*)d_ws;                                   // 4 MB
  float* Zrow = (float*)((char*)d_ws + (size_t)N_TOT * D_DIM * 2);  // 32 KB
  float* accs = Zrow + N_TOT;                                   // 2 floats

  hipMemsetAsync(Zrow, 0, (N_TOT + 2) * sizeof(float), stream);
  k_convert<<<(N_TOT * D_DIM / 4) / 256, 256, 0, stream>>>(hi, hj, hb);
  k_pos<<<(BATCH * 64) / 256, 256, 0, stream>>>(hi, hj, accs);
  dim3 g(64, 64);
  k_gemm<<<g, 256, 0, stream>>>(hb, Zrow);
  k_lse<<<N_TOT / 256, 256, 0, stream>>>(Zrow, accs);
  k_final<<<1, 1, 0, stream>>>(accs, out);
}

// Round 2
// 96.157 us; speedup vs baseline: 1.8952x; 1.8952x over previous
//
#include <hip/hip_runtime.h>
#include <hip/hip_bf16.h>
#include <stdint.h>

#define BATCH 4096
#define N_TOT 8192
#define D_DIM 256
#define SHIFT 150.0f
#define SQRT2 1.41421356237309515f

typedef __bf16 bf16_t;
typedef bf16_t bf16x8 __attribute__((ext_vector_type(8)));
typedef bf16_t bf16x4 __attribute__((ext_vector_type(4)));
typedef float f32x4 __attribute__((ext_vector_type(4)));

// global -> LDS direct copy, 16B per lane. LDS dest is wave-uniform base;
// HW scatters lane*16B.
__device__ __forceinline__ void gl_lds16(const void* g, void* l) {
  __builtin_amdgcn_global_load_lds(
      (const __attribute__((address_space(1))) void*)(uintptr_t)g,
      (__attribute__((address_space(3))) void*)(uint32_t)(uintptr_t)l,
      16, 0, 0);
}

// Fused: bf16 convert (x sqrt2), positive-pair dot partials, Zrow zero-init.
// 1024 blocks x 256 threads; wave w of block b owns row r = b*4+w.
__global__ void k_prep(const float* __restrict__ hi, const float* __restrict__ hj,
                       bf16_t* __restrict__ hb, float* __restrict__ Zrow,
                       float* __restrict__ posPartial) {
  const int wave = threadIdx.x >> 6, lane = threadIdx.x & 63;
  const int r = blockIdx.x * 4 + wave;
  const size_t off = (size_t)r * D_DIM + lane * 4;
  float4 a = *(const float4*)(hi + off);
  float4 b = *(const float4*)(hj + off);

  bf16x4 oa, ob;
  oa[0] = (bf16_t)(a.x * SQRT2); oa[1] = (bf16_t)(a.y * SQRT2);
  oa[2] = (bf16_t)(a.z * SQRT2); oa[3] = (bf16_t)(a.w * SQRT2);
  ob[0] = (bf16_t)(b.x * SQRT2); ob[1] = (bf16_t)(b.y * SQRT2);
  ob[2] = (bf16_t)(b.z * SQRT2); ob[3] = (bf16_t)(b.w * SQRT2);
  *(bf16x4*)(hb + off) = oa;
  *(bf16x4*)(hb + (size_t)BATCH * D_DIM + off) = ob;

  float d = a.x * b.x + a.y * b.y + a.z * b.z + a.w * b.w;
#pragma unroll
  for (int o = 32; o >= 1; o >>= 1) d += __shfl_xor(d, o);
  __shared__ float ps[4];
  if (lane == 0) ps[wave] = d;
  // zero 8 Zrow entries per block (8192 total over 1024 blocks)
  if (threadIdx.x < 8) Zrow[blockIdx.x * 8 + threadIdx.x] = 0.f;
  __syncthreads();
  if (threadIdx.x == 0) posPartial[blockIdx.x] = ps[0] + ps[1] + ps[2] + ps[3];
}

// Upper-triangular 128x128 tiles of sim = hb.hb^T; fused exp(sim-SHIFT) with
// row-sum AND (off-diag) col-sum accumulation into Zrow. 2080 blocks.
__global__ __launch_bounds__(256, 2) void k_gemm(const bf16_t* __restrict__ hb,
                                                 float* __restrict__ Zrow) {
  // decode linear block id -> (bi <= bj) triangular pair
  const int t = blockIdx.x;
  int bj = (int)((sqrtf(8.0f * (float)t + 1.0f) - 1.0f) * 0.5f);
  while ((bj + 1) * (bj + 2) / 2 <= t) ++bj;
  while (bj * (bj + 1) / 2 > t) --bj;
  const int bi = t - bj * (bj + 1) / 2;
  const int rBase = bi * 128;
  const int cBase = bj * 128;
  const bool diag = (bi == bj);

  __shared__ __align__(16) bf16_t As[128][64];
  __shared__ __align__(16) bf16_t Bs[128][64];
  const int tid = threadIdx.x;
  const int lane = tid & 63;
  const int wave = tid >> 6;

  // staging: waves 0,1 -> As halves; waves 2,3 -> Bs halves.
  // XOR-swizzle the 16B chunk on the GLOBAL side so LDS[row][c] holds global
  // chunk c ^ (row&7)  (row&7 == lane>>3 here) -> conflict-free frag reads.
  const int half = wave & 1;
  const size_t stageRow = (size_t)((wave < 2 ? rBase : cBase) + half * 64);
  const int c_src = (lane & 7) ^ (lane >> 3);
  const bf16_t* gsrc = hb + stageRow * D_DIM + (size_t)(lane >> 3) * D_DIM + c_src * 8;
  bf16_t* lbase = (wave < 2) ? &As[half * 64][0] : &Bs[half * 64][0];

  const int wm = wave >> 1, wn = wave & 1;
  const int quad = lane >> 4, l16 = lane & 15;
  const int sw = l16 & 7;  // read-side un-swizzle key

  f32x4 acc[4][4];
#pragma unroll
  for (int i = 0; i < 4; ++i)
#pragma unroll
    for (int j = 0; j < 4; ++j) acc[i][j] = (f32x4){0.f, 0.f, 0.f, 0.f};

#pragma unroll
  for (int kc = 0; kc < 4; ++kc) {
    __syncthreads();
#pragma unroll
    for (int i = 0; i < 8; ++i)
      gl_lds16(gsrc + (size_t)i * 8 * D_DIM + kc * 64, lbase + i * 8 * 64);
    __syncthreads();
#pragma unroll
    for (int ks = 0; ks < 2; ++ks) {
      bf16x8 af[4], bfr[4];
      const int chunk = ((ks * 4 + quad) ^ sw) * 8;
#pragma unroll
      for (int mt = 0; mt < 4; ++mt)
        af[mt] = *(const bf16x8*)&As[wm * 64 + mt * 16 + l16][chunk];
#pragma unroll
      for (int nt = 0; nt < 4; ++nt)
        bfr[nt] = *(const bf16x8*)&Bs[wn * 64 + nt * 16 + l16][chunk];
#pragma unroll
      for (int mt = 0; mt < 4; ++mt)
#pragma unroll
        for (int nt = 0; nt < 4; ++nt)
          acc[mt][nt] = __builtin_amdgcn_mfma_f32_16x16x32_bf16(af[mt], bfr[nt],
                                                                acc[mt][nt], 0, 0, 0);
    }
  }

  // epilogue: e = exp(sim - SHIFT); row sums always, col sums for off-diag
  // (symmetry: entry (r,c) also stands in for (c,r)).
  const int rW = rBase + wm * 64 + quad * 4;
  const int cW = cBase + wn * 64 + l16;
  float colAcc[4] = {0.f, 0.f, 0.f, 0.f};
#pragma unroll
  for (int mt = 0; mt < 4; ++mt) {
#pragma unroll
    for (int rg = 0; rg < 4; ++rg) {
      const int rr = rW + mt * 16 + rg;
      float s = 0.f;
#pragma unroll
      for (int nt = 0; nt < 4; ++nt) {
        float e = __expf(acc[mt][nt][rg] - SHIFT);
        if (diag && (rr == cW + nt * 16)) e = 0.f;  // mask self-similarity
        s += e;
        colAcc[nt] += e;
      }
      s += __shfl_xor(s, 1);
      s += __shfl_xor(s, 2);
      s += __shfl_xor(s, 4);
      s += __shfl_xor(s, 8);
      if (l16 == 0) atomicAdd(&Zrow[rr], s);
    }
  }
  if (!diag) {
#pragma unroll
    for (int nt = 0; nt < 4; ++nt) {
      float c = colAcc[nt];
      c += __shfl_xor(c, 16);
      c += __shfl_xor(c, 32);
      if (lane < 16) atomicAdd(&Zrow[cW + nt * 16], c);
    }
  }
}

// One block: loss = mean(log Z + SHIFT) - sum(dot)/2048
__global__ void k_finish(const float* __restrict__ Zrow,
                         const float* __restrict__ posPartial,
                         float* __restrict__ out) {
  const int t = threadIdx.x;  // 0..1023
  float sl = 0.f;
#pragma unroll
  for (int k = 0; k < 8; ++k) sl += __logf(Zrow[t + k * 1024]);
  float sp = posPartial[t];
#pragma unroll
  for (int o = 32; o >= 1; o >>= 1) {
    sl += __shfl_xor(sl, o);
    sp += __shfl_xor(sp, o);
  }
  __shared__ float pl[16], pp[16];
  const int wave = t >> 6, lane = t & 63;
  if (lane == 0) { pl[wave] = sl; pp[wave] = sp; }
  __syncthreads();
  if (t == 0) {
    float L = 0.f, P = 0.f;
    for (int i = 0; i < 16; ++i) { L += pl[i]; P += pp[i]; }
    out[0] = L / (float)N_TOT + SHIFT - P / 2048.0f;
  }
}

extern "C" void kernel_launch(void* const* d_in, const int* in_sizes, int n_in,
                              void* d_out, int out_size, void* d_ws, size_t ws_size,
                              hipStream_t stream) {
  const float* hi = (const float*)d_in[0];
  const float* hj = (const float*)d_in[1];
  float* out = (float*)d_out;

  bf16_t* hb = (bf16_t*)d_ws;                                        // 4 MB
  float* Zrow = (float*)((char*)d_ws + (size_t)N_TOT * D_DIM * 2);   // 32 KB
  float* posPartial = Zrow + N_TOT;                                  // 4 KB

  k_prep<<<1024, 256, 0, stream>>>(hi, hj, hb, Zrow, posPartial);
  k_gemm<<<2080, 256, 0, stream>>>(hb, Zrow);
  k_finish<<<1, 1024, 0, stream>>>(Zrow, posPartial, out);
}

// Round 3
// 95.671 us; speedup vs baseline: 1.9048x; 1.0051x over previous
//
#include <hip/hip_runtime.h>
#include <hip/hip_bf16.h>
#include <stdint.h>

#define BATCH 4096
#define N_TOT 8192
#define D_DIM 256
#define SHIFT 150.0f
#define SQRT2 1.41421356237309515f

typedef __bf16 bf16_t;
typedef bf16_t bf16x8 __attribute__((ext_vector_type(8)));
typedef bf16_t bf16x4 __attribute__((ext_vector_type(4)));
typedef float f32x4 __attribute__((ext_vector_type(4)));

// global -> LDS direct copy, 16B per lane. LDS dest is wave-uniform base;
// HW scatters lane*16B.
__device__ __forceinline__ void gl_lds16(const void* g, void* l) {
  __builtin_amdgcn_global_load_lds(
      (const __attribute__((address_space(1))) void*)(uintptr_t)g,
      (__attribute__((address_space(3))) void*)(uint32_t)(uintptr_t)l,
      16, 0, 0);
}

// Fused: bf16 convert (x sqrt2), positive-pair dot partials, Zrow zero-init.
// 1024 blocks x 256 threads; wave w of block b owns row r = b*4+w.
__global__ void k_prep(const float* __restrict__ hi, const float* __restrict__ hj,
                       bf16_t* __restrict__ hb, float* __restrict__ Zrow,
                       float* __restrict__ posPartial) {
  const int wave = threadIdx.x >> 6, lane = threadIdx.x & 63;
  const int r = blockIdx.x * 4 + wave;
  const size_t off = (size_t)r * D_DIM + lane * 4;
  float4 a = *(const float4*)(hi + off);
  float4 b = *(const float4*)(hj + off);

  bf16x4 oa, ob;
  oa[0] = (bf16_t)(a.x * SQRT2); oa[1] = (bf16_t)(a.y * SQRT2);
  oa[2] = (bf16_t)(a.z * SQRT2); oa[3] = (bf16_t)(a.w * SQRT2);
  ob[0] = (bf16_t)(b.x * SQRT2); ob[1] = (bf16_t)(b.y * SQRT2);
  ob[2] = (bf16_t)(b.z * SQRT2); ob[3] = (bf16_t)(b.w * SQRT2);
  *(bf16x4*)(hb + off) = oa;
  *(bf16x4*)(hb + (size_t)BATCH * D_DIM + off) = ob;

  float d = a.x * b.x + a.y * b.y + a.z * b.z + a.w * b.w;
#pragma unroll
  for (int o = 32; o >= 1; o >>= 1) d += __shfl_xor(d, o);
  __shared__ float ps[4];
  if (lane == 0) ps[wave] = d;
  // zero 8 Zrow entries per block (8192 total over 1024 blocks)
  if (threadIdx.x < 8) Zrow[blockIdx.x * 8 + threadIdx.x] = 0.f;
  __syncthreads();
  if (threadIdx.x == 0) posPartial[blockIdx.x] = ps[0] + ps[1] + ps[2] + ps[3];
}

// Upper-triangular 128x128 tiles of sim = hb.hb^T; fused exp(sim-SHIFT) with
// row-sum AND (off-diag) col-sum accumulation into Zrow. 2080 blocks.
// launch_bounds(256,4): VGPR<=128, LDS 32KB -> 4 blocks/CU resident so
// sibling blocks' compute covers each block's barrier-drain staging stall.
__global__ __launch_bounds__(256, 4) void k_gemm(const bf16_t* __restrict__ hb,
                                                 float* __restrict__ Zrow) {
  // decode linear block id -> (bi <= bj) triangular pair
  const int t = blockIdx.x;
  int bj = (int)((sqrtf(8.0f * (float)t + 1.0f) - 1.0f) * 0.5f);
  while ((bj + 1) * (bj + 2) / 2 <= t) ++bj;
  while (bj * (bj + 1) / 2 > t) --bj;
  const int bi = t - bj * (bj + 1) / 2;
  const int rBase = bi * 128;
  const int cBase = bj * 128;
  const bool diag = (bi == bj);

  __shared__ __align__(16) bf16_t As[128][64];
  __shared__ __align__(16) bf16_t Bs[128][64];
  const int tid = threadIdx.x;
  const int lane = tid & 63;
  const int wave = tid >> 6;

  // staging: waves 0,1 -> As halves; waves 2,3 -> Bs halves.
  // XOR-swizzle the 16B chunk on the GLOBAL side so LDS[row][c] holds global
  // chunk c ^ (row&7)  (row&7 == lane>>3 here) -> conflict-free frag reads.
  const int half = wave & 1;
  const size_t stageRow = (size_t)((wave < 2 ? rBase : cBase) + half * 64);
  const int c_src = (lane & 7) ^ (lane >> 3);
  const bf16_t* gsrc = hb + stageRow * D_DIM + (size_t)(lane >> 3) * D_DIM + c_src * 8;
  bf16_t* lbase = (wave < 2) ? &As[half * 64][0] : &Bs[half * 64][0];

  const int wm = wave >> 1, wn = wave & 1;
  const int quad = lane >> 4, l16 = lane & 15;
  const int sw = l16 & 7;  // read-side un-swizzle key

  f32x4 acc[4][4];
#pragma unroll
  for (int i = 0; i < 4; ++i)
#pragma unroll
    for (int j = 0; j < 4; ++j) acc[i][j] = (f32x4){0.f, 0.f, 0.f, 0.f};

#pragma unroll
  for (int kc = 0; kc < 4; ++kc) {
    __syncthreads();
#pragma unroll
    for (int i = 0; i < 8; ++i)
      gl_lds16(gsrc + (size_t)i * 8 * D_DIM + kc * 64, lbase + i * 8 * 64);
    __syncthreads();
#pragma unroll
    for (int ks = 0; ks < 2; ++ks) {
      bf16x8 af[4], bfr[4];
      const int chunk = ((ks * 4 + quad) ^ sw) * 8;
#pragma unroll
      for (int mt = 0; mt < 4; ++mt)
        af[mt] = *(const bf16x8*)&As[wm * 64 + mt * 16 + l16][chunk];
#pragma unroll
      for (int nt = 0; nt < 4; ++nt)
        bfr[nt] = *(const bf16x8*)&Bs[wn * 64 + nt * 16 + l16][chunk];
#pragma unroll
      for (int mt = 0; mt < 4; ++mt)
#pragma unroll
        for (int nt = 0; nt < 4; ++nt)
          acc[mt][nt] = __builtin_amdgcn_mfma_f32_16x16x32_bf16(af[mt], bfr[nt],
                                                                acc[mt][nt], 0, 0, 0);
    }
  }

  // epilogue: e = exp(sim - SHIFT); row sums always, col sums for off-diag
  // (symmetry: entry (r,c) also stands in for (c,r)).
  const int rW = rBase + wm * 64 + quad * 4;
  const int cW = cBase + wn * 64 + l16;
  float colAcc[4] = {0.f, 0.f, 0.f, 0.f};
#pragma unroll
  for (int mt = 0; mt < 4; ++mt) {
#pragma unroll
    for (int rg = 0; rg < 4; ++rg) {
      const int rr = rW + mt * 16 + rg;
      float s = 0.f;
#pragma unroll
      for (int nt = 0; nt < 4; ++nt) {
        float e = __expf(acc[mt][nt][rg] - SHIFT);
        if (diag && (rr == cW + nt * 16)) e = 0.f;  // mask self-similarity
        s += e;
        colAcc[nt] += e;
      }
      s += __shfl_xor(s, 1);
      s += __shfl_xor(s, 2);
      s += __shfl_xor(s, 4);
      s += __shfl_xor(s, 8);
      if (l16 == 0) atomicAdd(&Zrow[rr], s);
    }
  }
  if (!diag) {
#pragma unroll
    for (int nt = 0; nt < 4; ++nt) {
      float c = colAcc[nt];
      c += __shfl_xor(c, 16);
      c += __shfl_xor(c, 32);
      if (lane < 16) atomicAdd(&Zrow[cW + nt * 16], c);
    }
  }
}

// One block: loss = mean(log Z + SHIFT) - sum(dot)/2048
__global__ void k_finish(const float* __restrict__ Zrow,
                         const float* __restrict__ posPartial,
                         float* __restrict__ out) {
  const int t = threadIdx.x;  // 0..1023
  float4 z0 = *(const float4*)(Zrow + t * 8);
  float4 z1 = *(const float4*)(Zrow + t * 8 + 4);
  float sl = __logf(z0.x) + __logf(z0.y) + __logf(z0.z) + __logf(z0.w) +
             __logf(z1.x) + __logf(z1.y) + __logf(z1.z) + __logf(z1.w);
  float sp = posPartial[t];
#pragma unroll
  for (int o = 32; o >= 1; o >>= 1) {
    sl += __shfl_xor(sl, o);
    sp += __shfl_xor(sp, o);
  }
  __shared__ float pl[16], pp[16];
  const int wave = t >> 6, lane = t & 63;
  if (lane == 0) { pl[wave] = sl; pp[wave] = sp; }
  __syncthreads();
  if (t == 0) {
    float L = 0.f, P = 0.f;
    for (int i = 0; i < 16; ++i) { L += pl[i]; P += pp[i]; }
    out[0] = L / (float)N_TOT + SHIFT - P / 2048.0f;
  }
}

extern "C" void kernel_launch(void* const* d_in, const int* in_sizes, int n_in,
                              void* d_out, int out_size, void* d_ws, size_t ws_size,
                              hipStream_t stream) {
  const float* hi = (const float*)d_in[0];
  const float* hj = (const float*)d_in[1];
  float* out = (float*)d_out;

  bf16_t* hb = (bf16_t*)d_ws;                                        // 4 MB
  float* Zrow = (float*)((char*)d_ws + (size_t)N_TOT * D_DIM * 2);   // 32 KB
  float* posPartial = Zrow + N_TOT;                                  // 4 KB

  k_prep<<<1024, 256, 0, stream>>>(hi, hj, hb, Zrow, posPartial);
  k_gemm<<<2080, 256, 0, stream>>>(hb, Zrow);
  k_finish<<<1, 1024, 0, stream>>>(Zrow, posPartial, out);
}